// Round 1
// 1038.822 us; speedup vs baseline: 1.0179x; 1.0179x over previous
//
#include <hip/hip_runtime.h>

typedef __bf16 bf16;
typedef __bf16 bf16x8 __attribute__((ext_vector_type(8)));
typedef __bf16 bf16x4 __attribute__((ext_vector_type(4)));
typedef float  f32x4  __attribute__((ext_vector_type(4)));

#define MFMA16(a, b, c) __builtin_amdgcn_mfma_f32_16x16x32_bf16(a, b, c, 0, 0, 0)

__device__ __forceinline__ void gload_lds16(const void* g, void* l) {
    __builtin_amdgcn_global_load_lds((const __attribute__((address_space(1))) void*)g,
                                     (__attribute__((address_space(3))) void*)l, 16, 0, 0);
}

// window-order row -> original-order row (inverse of roll(-4,-4)+partition)
__device__ __forceinline__ long win2orig(long r) {
    long b = r >> 12; int rem = (int)(r & 4095);
    int widx = rem >> 6, t = rem & 63;
    int rp = ((widx >> 3) << 3) + (t >> 3), cp = ((widx & 7) << 3) + (t & 7);
    int rr = (rp + 4) & 63, cc = (cp + 4) & 63;
    return (b << 12) + rr * 64 + cc;
}

// ---------------------------------------------------------------- GEMM
// C[M,N] = A[M,K] (bf16) * Bt[N,K]^T (bf16) + bias, optional gelu.
// 128x128 tile, BK=32, global_load_lds w=16, fragment-linear LDS.
// This round: XCD-chunked block swizzle (T1), double-buffered 2-phase K-loop
// (T3-minimum: prefetch kt+1 while computing kt, ONE barrier per kt), and
// sigmoid-form GELU (7 VALU ops vs ~12).
template <int GELU>
__global__ __launch_bounds__(256) void gemm_bt(const bf16* __restrict__ A,
                                               const bf16* __restrict__ Bt,
                                               const float* __restrict__ bias,
                                               bf16* __restrict__ C,
                                               int M, int N, int K) {
    __shared__ bf16 As[2][4096];
    __shared__ bf16 Bs[2][4096];
    const int t = threadIdx.x;
    const int w = t >> 6, l = t & 63;
    const int l15 = l & 15, q4 = l >> 4;
    const int wm = w >> 1, wn = w & 1;

    // T1: chunked XCD swizzle. All launches have nwg % 8 == 0.
    // XCD k gets the contiguous chunk [k*nwg/8, (k+1)*nwg/8); within a chunk
    // consecutive ids iterate blockIdx.x fastest -> the gx column-tiles of one
    // A row-block run back-to-back on the SAME XCD -> A tile stays in that L2.
    const unsigned gx = gridDim.x;
    const unsigned nwg = gx * gridDim.y;
    const unsigned id0 = blockIdx.y * gx + blockIdx.x;
    const unsigned swz = (id0 & 7u) * (nwg >> 3) + (id0 >> 3);
    const unsigned bx = swz % gx, by = swz / gx;

    const long row0 = (long)by * 128;
    const int col0 = (int)bx * 128;

    const bf16* aP = A + (row0 + w * 16 + l15) * (long)K + q4 * 8;
    const bf16* bP = Bt + (long)(col0 + w * 16 + l15) * K + q4 * 8;
    const long step64 = 64L * K;

    f32x4 acc[4][4];
#pragma unroll
    for (int i = 0; i < 4; i++)
#pragma unroll
        for (int j = 0; j < 4; j++)
#pragma unroll
            for (int r = 0; r < 4; r++) acc[i][j][r] = 0.f;

    const int KT = K >> 5;

    // prologue: stage tile 0 into buffer 0
    gload_lds16(aP,          &As[0][w * 512]);
    gload_lds16(aP + step64, &As[0][w * 512 + 2048]);
    gload_lds16(bP,          &Bs[0][w * 512]);
    gload_lds16(bP + step64, &Bs[0][w * 512 + 2048]);
    aP += 32; bP += 32;
    __syncthreads();  // drains vmcnt(0): tile 0 resident

    int cur = 0;
    for (int kt = 0; kt < KT; ++kt) {
        // prefetch next tile into the other buffer (overlaps ds_read + MFMA)
        if (kt + 1 < KT) {
            gload_lds16(aP,          &As[cur ^ 1][w * 512]);
            gload_lds16(aP + step64, &As[cur ^ 1][w * 512 + 2048]);
            gload_lds16(bP,          &Bs[cur ^ 1][w * 512]);
            gload_lds16(bP + step64, &Bs[cur ^ 1][w * 512 + 2048]);
            aP += 32; bP += 32;
        }
        bf16x8 af[4], bfv[4];
#pragma unroll
        for (int mi = 0; mi < 4; mi++) af[mi] = *(const bf16x8*)(&As[cur][(wm * 4 + mi) * 512 + l * 8]);
#pragma unroll
        for (int nj = 0; nj < 4; nj++) bfv[nj] = *(const bf16x8*)(&Bs[cur][(wn * 4 + nj) * 512 + l * 8]);
#pragma unroll
        for (int mi = 0; mi < 4; mi++)
#pragma unroll
            for (int nj = 0; nj < 4; nj++) acc[mi][nj] = MFMA16(af[mi], bfv[nj], acc[mi][nj]);
        __syncthreads();  // drains vmcnt(0) (prefetch done) + all waves done reading cur
        cur ^= 1;
    }

    float cb[4];
#pragma unroll
    for (int nj = 0; nj < 4; nj++) cb[nj] = bias[col0 + wn * 64 + nj * 16 + l15];

#pragma unroll
    for (int mi = 0; mi < 4; mi++) {
#pragma unroll
        for (int reg = 0; reg < 4; reg++) {
            long r = row0 + wm * 64 + mi * 16 + q4 * 4 + reg;
            bf16* cpn = C + r * (long)N + col0 + wn * 64 + l15;
#pragma unroll
            for (int nj = 0; nj < 4; nj++) {
                float v = acc[mi][nj][reg] + cb[nj];
                if (GELU) {
                    // tanh-gelu == v * sigmoid(2u), u = 0.79788456*(v + 0.044715 v^3)
                    // exp(-2u) = exp2(v*(c0 + c1*v^2)), c0 = -2.30218094, c1 = c0*0.044715
                    float v2 = v * v;
                    float tt = v * fmaf(v2, -0.10294702f, -2.30218094f);
                    float e = __builtin_amdgcn_exp2f(tt);
                    v = v * __builtin_amdgcn_rcpf(1.f + e);
                }
                cpn[nj * 16] = (bf16)v;
            }
        }
    }
}

// ---------------------------------------------------------------- attention
// One wave per (window, head). qkv rows in window order.
__global__ __launch_bounds__(64) void attn_kernel(const bf16* __restrict__ qkv,
                                                  const float* __restrict__ bias16,
                                                  const float* __restrict__ logit_scale,
                                                  bf16* __restrict__ outp) {
    __shared__ bf16 P[64 * 72];
    __shared__ bf16 Vt[32 * 72];
    const int unit = blockIdx.x;
    const int w = unit >> 3, h = unit & 7;
    const int l = threadIdx.x;
    const int l15 = l & 15, q4 = l >> 4;
    const bf16* base = qkv + (long)w * 64 * 768;

    {  // stage V^T: lane l holds token l
        const bf16* vp = base + l * 768 + 512 + h * 32;
#pragma unroll
        for (int c = 0; c < 4; c++) {
            bf16x8 vv = *(const bf16x8*)(vp + c * 8);
#pragma unroll
            for (int j = 0; j < 8; j++) Vt[(c * 8 + j) * 72 + l] = vv[j];
        }
    }

    const float scale = __expf(fminf(logit_scale[h], 4.605170186f));

    bf16x8 qf[4], kf[4];
#pragma unroll
    for (int mi = 0; mi < 4; mi++) {  // l2-normalized Q fragments
        const bf16* p = base + (mi * 16 + l15) * 768 + h * 32 + q4 * 8;
        bf16x8 xv = *(const bf16x8*)p;
        float fv[8]; float ss = 0.f;
#pragma unroll
        for (int j = 0; j < 8; j++) { fv[j] = (float)xv[j]; ss += fv[j] * fv[j]; }
        ss += __shfl_xor(ss, 16); ss += __shfl_xor(ss, 32);
        float rs = rsqrtf(fmaxf(ss, 1e-12f));
#pragma unroll
        for (int j = 0; j < 8; j++) qf[mi][j] = (bf16)(fv[j] * rs);
    }
#pragma unroll
    for (int nj = 0; nj < 4; nj++) {  // l2-normalized K fragments
        const bf16* p = base + (nj * 16 + l15) * 768 + 256 + h * 32 + q4 * 8;
        bf16x8 xv = *(const bf16x8*)p;
        float fv[8]; float ss = 0.f;
#pragma unroll
        for (int j = 0; j < 8; j++) { fv[j] = (float)xv[j]; ss += fv[j] * fv[j]; }
        ss += __shfl_xor(ss, 16); ss += __shfl_xor(ss, 32);
        float rs = rsqrtf(fmaxf(ss, 1e-12f));
#pragma unroll
        for (int j = 0; j < 8; j++) kf[nj][j] = (bf16)(fv[j] * rs);
    }

    f32x4 acc[4][4];
#pragma unroll
    for (int i = 0; i < 4; i++)
#pragma unroll
        for (int j = 0; j < 4; j++)
#pragma unroll
            for (int r = 0; r < 4; r++) acc[i][j][r] = 0.f;
#pragma unroll
    for (int mi = 0; mi < 4; mi++)
#pragma unroll
        for (int nj = 0; nj < 4; nj++) acc[mi][nj] = MFMA16(qf[mi], kf[nj], acc[mi][nj]);

    // scale + CPB bias + shift mask
    const int widx = w & 63, wr = widx >> 3, wc = widx & 7;
    const bool edge = (wr == 7) || (wc == 7);
    int crid[4];
    if (edge) {
#pragma unroll
        for (int nj = 0; nj < 4; nj++) {
            int m = nj * 16 + l15;
            int R = wr * 8 + (m >> 3), Cc = wc * 8 + (m & 7);
            crid[nj] = ((R < 56) ? 0 : (R < 60 ? 1 : 2)) * 3 + ((Cc < 56) ? 0 : (Cc < 60 ? 1 : 2));
        }
    }
    const float* bh = bias16 + h * 4096;
#pragma unroll
    for (int mi = 0; mi < 4; mi++) {
#pragma unroll
        for (int reg = 0; reg < 4; reg++) {
            int n = mi * 16 + q4 * 4 + reg;
            const float* bp = bh + n * 64;
            int nrid = 0;
            if (edge) {
                int R = wr * 8 + (n >> 3), Cc = wc * 8 + (n & 7);
                nrid = ((R < 56) ? 0 : (R < 60 ? 1 : 2)) * 3 + ((Cc < 56) ? 0 : (Cc < 60 ? 1 : 2));
            }
#pragma unroll
            for (int nj = 0; nj < 4; nj++) {
                float v = acc[mi][nj][reg] * scale + bp[nj * 16 + l15];
                if (edge && nrid != crid[nj]) v -= 100.f;
                acc[mi][nj][reg] = v;
            }
        }
    }

    // row softmax (row = 16 lanes sharing q4, across 4 nj regs)
#pragma unroll
    for (int mi = 0; mi < 4; mi++) {
#pragma unroll
        for (int reg = 0; reg < 4; reg++) {
            float mx = fmaxf(fmaxf(acc[mi][0][reg], acc[mi][1][reg]),
                             fmaxf(acc[mi][2][reg], acc[mi][3][reg]));
            mx = fmaxf(mx, __shfl_xor(mx, 1));
            mx = fmaxf(mx, __shfl_xor(mx, 2));
            mx = fmaxf(mx, __shfl_xor(mx, 4));
            mx = fmaxf(mx, __shfl_xor(mx, 8));
            float s = 0.f;
#pragma unroll
            for (int nj = 0; nj < 4; nj++) {
                float e = __expf(acc[mi][nj][reg] - mx);
                acc[mi][nj][reg] = e; s += e;
            }
            s += __shfl_xor(s, 1); s += __shfl_xor(s, 2);
            s += __shfl_xor(s, 4); s += __shfl_xor(s, 8);
            float inv = 1.f / s;
            int n = mi * 16 + q4 * 4 + reg;
#pragma unroll
            for (int nj = 0; nj < 4; nj++)
                P[n * 72 + nj * 16 + l15] = (bf16)(acc[mi][nj][reg] * inv);
        }
    }
    __syncthreads();

    // O = P @ V  (K=64 in two 32-steps)
    f32x4 o[4][2];
#pragma unroll
    for (int i = 0; i < 4; i++)
#pragma unroll
        for (int j = 0; j < 2; j++)
#pragma unroll
            for (int r = 0; r < 4; r++) o[i][j][r] = 0.f;
#pragma unroll
    for (int ks = 0; ks < 2; ks++) {
        bf16x8 vf[2];
#pragma unroll
        for (int nj = 0; nj < 2; nj++) vf[nj] = *(const bf16x8*)(&Vt[(nj * 16 + l15) * 72 + ks * 32 + q4 * 8]);
#pragma unroll
        for (int mi = 0; mi < 4; mi++) {
            bf16x8 pf = *(const bf16x8*)(&P[(mi * 16 + l15) * 72 + ks * 32 + q4 * 8]);
#pragma unroll
            for (int nj = 0; nj < 2; nj++) o[mi][nj] = MFMA16(pf, vf[nj], o[mi][nj]);
        }
    }

    bf16* op = outp + (long)w * 64 * 256 + h * 32;
#pragma unroll
    for (int mi = 0; mi < 4; mi++)
#pragma unroll
        for (int reg = 0; reg < 4; reg++) {
            int tok = mi * 16 + q4 * 4 + reg;
#pragma unroll
            for (int nj = 0; nj < 2; nj++)
                op[tok * 256 + nj * 16 + l15] = (bf16)o[mi][nj][reg];
        }
}

// ---------------------------------------------------------------- norms
// norm1: rows in window order; scatter to orig order: x1 = x + LN(proj_out)
__global__ __launch_bounds__(256) void norm1_kernel(const bf16* __restrict__ pin,
                                                    const float* __restrict__ x,
                                                    const float* __restrict__ g,
                                                    const float* __restrict__ bb,
                                                    bf16* __restrict__ x1h) {
    const int tid = threadIdx.x;
    const int wid = tid >> 6, l = tid & 63;
    const long rl = (long)blockIdx.x * 4 + wid;
    bf16x4 v4 = *(const bf16x4*)(pin + rl * 256 + l * 4);
    float v[4]; float s = 0.f, sq = 0.f;
#pragma unroll
    for (int c = 0; c < 4; c++) { v[c] = (float)v4[c]; s += v[c]; sq += v[c] * v[c]; }
#pragma unroll
    for (int off = 1; off < 64; off <<= 1) { s += __shfl_xor(s, off); sq += __shfl_xor(sq, off); }
    float mu = s * 0.00390625f;
    float var = sq * 0.00390625f - mu * mu;
    float rstd = rsqrtf(var + 1e-6f);
    long orig = win2orig(rl);
    float4 xv = *(const float4*)(x + orig * 256 + l * 4);
    float4 gv = *(const float4*)(g + l * 4);
    float4 bv = *(const float4*)(bb + l * 4);
    bf16x4 oh;
    oh[0] = (bf16)(xv.x + ((v[0] - mu) * rstd * gv.x + bv.x));
    oh[1] = (bf16)(xv.y + ((v[1] - mu) * rstd * gv.y + bv.y));
    oh[2] = (bf16)(xv.z + ((v[2] - mu) * rstd * gv.z + bv.z));
    oh[3] = (bf16)(xv.w + ((v[3] - mu) * rstd * gv.w + bv.w));
    *(bf16x4*)(x1h + orig * 256 + l * 4) = oh;
}

// norm2: out = x1 + LN(fc2_out), all in orig order
__global__ __launch_bounds__(256) void norm2_kernel(const bf16* __restrict__ hin,
                                                    const bf16* __restrict__ x1h,
                                                    const float* __restrict__ g,
                                                    const float* __restrict__ bb,
                                                    float* __restrict__ outp) {
    const int tid = threadIdx.x;
    const int wid = tid >> 6, l = tid & 63;
    const long rl = (long)blockIdx.x * 4 + wid;
    bf16x4 v4 = *(const bf16x4*)(hin + rl * 256 + l * 4);
    float v[4]; float s = 0.f, sq = 0.f;
#pragma unroll
    for (int c = 0; c < 4; c++) { v[c] = (float)v4[c]; s += v[c]; sq += v[c] * v[c]; }
#pragma unroll
    for (int off = 1; off < 64; off <<= 1) { s += __shfl_xor(s, off); sq += __shfl_xor(sq, off); }
    float mu = s * 0.00390625f;
    float var = sq * 0.00390625f - mu * mu;
    float rstd = rsqrtf(var + 1e-6f);
    bf16x4 xv4 = *(const bf16x4*)(x1h + rl * 256 + l * 4);
    float4 gv = *(const float4*)(g + l * 4);
    float4 bv = *(const float4*)(bb + l * 4);
    float4 ov;
    ov.x = (float)xv4[0] + ((v[0] - mu) * rstd * gv.x + bv.x);
    ov.y = (float)xv4[1] + ((v[1] - mu) * rstd * gv.y + bv.y);
    ov.z = (float)xv4[2] + ((v[2] - mu) * rstd * gv.z + bv.z);
    ov.w = (float)xv4[3] + ((v[3] - mu) * rstd * gv.w + bv.w);
    *(float4*)(outp + rl * 256 + l * 4) = ov;
}

// ---------------------------------------------------------------- small prep
// gather rows (window order) from x (orig order, fp32), cast to bf16
__global__ __launch_bounds__(256) void gather_cast(const float* __restrict__ x,
                                                   bf16* __restrict__ out) {
    const int tid = threadIdx.x;
    const int wid = tid >> 6, l = tid & 63;
    const long rl = (long)blockIdx.x * 4 + wid;
    long orig = win2orig(rl);
    float4 v = *(const float4*)(x + orig * 256 + l * 4);
    bf16x4 o = {(bf16)v.x, (bf16)v.y, (bf16)v.z, (bf16)v.w};
    *(bf16x4*)(out + rl * 256 + l * 4) = o;
}

// out[N,K] = cast(in[K,N]^T)
__global__ void transpose_cast(const float* __restrict__ in, bf16* __restrict__ out, int K, int N) {
    int id = blockIdx.x * 256 + threadIdx.x;
    if (id < K * N) {
        int n = id / K, k = id - n * K;
        out[id] = (bf16)in[k * N + n];
    }
}

__global__ void build_qkv_bias(const float* __restrict__ qb, const float* __restrict__ vb,
                               float* __restrict__ out) {
    int i = blockIdx.x * 256 + threadIdx.x;
    if (i < 768) out[i] = (i < 256) ? qb[i] : ((i < 512) ? 0.f : vb[i - 512]);
}

__device__ __forceinline__ float cpcoord(int d) {
    float v = (float)d * (8.0f / 7.0f);
    float r = log2f(fabsf(v) + 1.0f) * (1.0f / 3.0f);
    return v < 0.f ? -r : r;
}

__global__ void cpb1(const float* __restrict__ w1, const float* __restrict__ b1,
                     const float* __restrict__ w2, float* __restrict__ tbl) {
    int a = threadIdx.x;
    if (a >= 225) return;
    int i = a / 15, j = a - i * 15;
    float t0 = cpcoord(i - 7), t1 = cpcoord(j - 7);
    float acc[8];
#pragma unroll
    for (int o = 0; o < 8; o++) acc[o] = 0.f;
    for (int jj = 0; jj < 512; jj++) {
        float hv = fmaf(t0, w1[jj], fmaf(t1, w1[512 + jj], b1[jj]));
        hv = fmaxf(hv, 0.f);
#pragma unroll
        for (int o = 0; o < 8; o++) acc[o] = fmaf(hv, w2[jj * 8 + o], acc[o]);
    }
#pragma unroll
    for (int o = 0; o < 8; o++) tbl[a * 8 + o] = acc[o];
}

__global__ void cpb2(const float* __restrict__ tbl, float* __restrict__ bias16) {
    int id = blockIdx.x * 256 + threadIdx.x;
    if (id >= 32768) return;
    int h = id >> 12, n = (id >> 6) & 63, m = id & 63;
    int r0 = (n >> 3) - (m >> 3) + 7;
    int r1 = (n & 7) - (m & 7) + 7;
    float v = tbl[(r0 * 15 + r1) * 8 + h];
    bias16[id] = 16.f / (1.f + __expf(-v));
}

// ---------------------------------------------------------------- launch
extern "C" void kernel_launch(void* const* d_in, const int* in_sizes, int n_in,
                              void* d_out, int out_size, void* d_ws, size_t ws_size,
                              hipStream_t stream) {
    const float* x   = (const float*)d_in[0];
    const float* qkvw= (const float*)d_in[1];
    const float* qb  = (const float*)d_in[2];
    const float* vb  = (const float*)d_in[3];
    const float* ls  = (const float*)d_in[4];
    const float* cw1 = (const float*)d_in[5];
    const float* cb1 = (const float*)d_in[6];
    const float* cw2 = (const float*)d_in[7];
    const float* pw  = (const float*)d_in[8];
    const float* pb  = (const float*)d_in[9];
    const float* n1s = (const float*)d_in[10];
    const float* n1b = (const float*)d_in[11];
    const float* n2s = (const float*)d_in[12];
    const float* n2b = (const float*)d_in[13];
    const float* f1w = (const float*)d_in[14];
    const float* f1b = (const float*)d_in[15];
    const float* f2w = (const float*)d_in[16];
    const float* f2b = (const float*)d_in[17];

    char* ws = (char*)d_ws;
    if (ws_size < 471859200UL) return;  // peak scratch = 450 MiB (harness gives 512 MiB)
    bf16*  qkvBt   = (bf16*)(ws + 0);
    bf16*  projBt  = (bf16*)(ws + 393216);
    bf16*  fc1Bt   = (bf16*)(ws + 524288);
    bf16*  fc2Bt   = (bf16*)(ws + 1048576);
    float* qkvBias = (float*)(ws + 1572864);
    float* cpbTbl  = (float*)(ws + 1575936);
    float* bias16  = (float*)(ws + 1583360);
    // big buffers (offsets in bytes from ws)
    bf16* xbf     = (bf16*)(ws + 2097152);     // 131072x256  (window order), 64 MiB
    bf16* qkvBuf  = (bf16*)(ws + 69206016);    // 131072x768, 192 MiB
    bf16* attnOut = (bf16*)(ws + 270532608);   // 131072x256, 64 MiB
    bf16* projOut = (bf16*)(ws + 337641472);   // 131072x256, 64 MiB
    bf16* x1h     = (bf16*)(ws + 404750336);   // 131072x256 (orig order), 64 MiB
    bf16* hBuf    = (bf16*)(ws + 2097152);     // 131072x1024, 256 MiB (aliases xbf+qkvBuf, dead)
    bf16* fc2Out  = (bf16*)(ws + 337641472);   // aliases projOut (dead after norm1)

    transpose_cast<<<768, 256, 0, stream>>>(qkvw, qkvBt, 256, 768);
    transpose_cast<<<256, 256, 0, stream>>>(pw, projBt, 256, 256);
    transpose_cast<<<1024, 256, 0, stream>>>(f1w, fc1Bt, 256, 1024);
    transpose_cast<<<1024, 256, 0, stream>>>(f2w, fc2Bt, 1024, 256);
    build_qkv_bias<<<3, 256, 0, stream>>>(qb, vb, qkvBias);
    cpb1<<<1, 256, 0, stream>>>(cw1, cb1, cw2, cpbTbl);
    cpb2<<<128, 256, 0, stream>>>(cpbTbl, bias16);

    gather_cast<<<32768, 256, 0, stream>>>(x, xbf);
    gemm_bt<0><<<dim3(6, 1024), 256, 0, stream>>>(xbf, qkvBt, qkvBias, qkvBuf, 131072, 768, 256);
    attn_kernel<<<16384, 64, 0, stream>>>(qkvBuf, bias16, ls, attnOut);
    gemm_bt<0><<<dim3(2, 1024), 256, 0, stream>>>(attnOut, projBt, pb, projOut, 131072, 256, 256);
    norm1_kernel<<<32768, 256, 0, stream>>>(projOut, x, n1s, n1b, x1h);
    gemm_bt<1><<<dim3(8, 1024), 256, 0, stream>>>(x1h, fc1Bt, f1b, hBuf, 131072, 1024, 256);
    gemm_bt<0><<<dim3(2, 1024), 256, 0, stream>>>(hBuf, fc2Bt, f2b, fc2Out, 131072, 256, 1024);
    norm2_kernel<<<32768, 256, 0, stream>>>(fc2Out, x1h, n2s, n2b, (float*)d_out);
}

// Round 2
// 1029.892 us; speedup vs baseline: 1.0267x; 1.0087x over previous
//
#include <hip/hip_runtime.h>

typedef __bf16 bf16;
typedef __bf16 bf16x8 __attribute__((ext_vector_type(8)));
typedef __bf16 bf16x4 __attribute__((ext_vector_type(4)));
typedef float  f32x4  __attribute__((ext_vector_type(4)));

#define MFMA16(a, b, c) __builtin_amdgcn_mfma_f32_16x16x32_bf16(a, b, c, 0, 0, 0)

__device__ __forceinline__ void gload_lds16(const void* g, void* l) {
    __builtin_amdgcn_global_load_lds((const __attribute__((address_space(1))) void*)g,
                                     (__attribute__((address_space(3))) void*)l, 16, 0, 0);
}

// window-order row -> original-order row (inverse of roll(-4,-4)+partition)
__device__ __forceinline__ long win2orig(long r) {
    long b = r >> 12; int rem = (int)(r & 4095);
    int widx = rem >> 6, t = rem & 63;
    int rp = ((widx >> 3) << 3) + (t >> 3), cp = ((widx & 7) << 3) + (t & 7);
    int rr = (rp + 4) & 63, cc = (cp + 4) & 63;
    return (b << 12) + rr * 64 + cc;
}

// ---------------------------------------------------------------- GEMM
// C[M,N] = A[M,K] (bf16) * Bt[N,K]^T (bf16) + bias, optional gelu.
// 128x128 tile, BK=32, global_load_lds w=16, fragment-linear LDS.
// Round 2: T4 counted-vmcnt pipeline with raw s_barrier (no __syncthreads
// vmcnt(0) drain). 2-deep prefetch: tile kt+2 issued while MFMA on kt runs;
// wait is vmcnt(4) (prefetched tile stays in flight across the barrier).
template <int GELU>
__global__ __launch_bounds__(256) void gemm_bt(const bf16* __restrict__ A,
                                               const bf16* __restrict__ Bt,
                                               const float* __restrict__ bias,
                                               bf16* __restrict__ C,
                                               int M, int N, int K) {
    __shared__ bf16 As[2][4096];
    __shared__ bf16 Bs[2][4096];
    const int t = threadIdx.x;
    const int w = t >> 6, l = t & 63;
    const int l15 = l & 15, q4 = l >> 4;
    const int wm = w >> 1, wn = w & 1;

    // T1: chunked XCD swizzle (all launches have nwg % 8 == 0).
    const unsigned gx = gridDim.x;
    const unsigned nwg = gx * gridDim.y;
    const unsigned id0 = blockIdx.y * gx + blockIdx.x;
    const unsigned swz = (id0 & 7u) * (nwg >> 3) + (id0 >> 3);
    const unsigned bx = swz % gx, by = swz / gx;

    const long row0 = (long)by * 128;
    const int col0 = (int)bx * 128;

    const bf16* aP = A + (row0 + w * 16 + l15) * (long)K + q4 * 8;
    const bf16* bP = Bt + (long)(col0 + w * 16 + l15) * K + q4 * 8;
    const long step64 = 64L * K;

    f32x4 acc[4][4];
#pragma unroll
    for (int i = 0; i < 4; i++)
#pragma unroll
        for (int j = 0; j < 4; j++)
#pragma unroll
            for (int r = 0; r < 4; r++) acc[i][j][r] = 0.f;

    const int KT = K >> 5;  // all call sites have KT >= 8

    // prologue: 2-deep prefetch (tiles 0 and 1), no drain.
    gload_lds16(aP,          &As[0][w * 512]);
    gload_lds16(aP + step64, &As[0][w * 512 + 2048]);
    gload_lds16(bP,          &Bs[0][w * 512]);
    gload_lds16(bP + step64, &Bs[0][w * 512 + 2048]);
    aP += 32; bP += 32;
    gload_lds16(aP,          &As[1][w * 512]);
    gload_lds16(aP + step64, &As[1][w * 512 + 2048]);
    gload_lds16(bP,          &Bs[1][w * 512]);
    gload_lds16(bP + step64, &Bs[1][w * 512 + 2048]);
    aP += 32; bP += 32;

    for (int kt = 0; kt < KT; ++kt) {
        const int cur = kt & 1;
        // wait for tile kt only: the 4 newer loads (tile kt+1) stay in flight.
        if (kt < KT - 1) { asm volatile("s_waitcnt vmcnt(4)" ::: "memory"); }
        else             { asm volatile("s_waitcnt vmcnt(0)" ::: "memory"); }
        __builtin_amdgcn_s_barrier();          // all waves' tile-kt loads landed
        asm volatile("" ::: "memory");         // pin ds_read below the barrier

        bf16x8 af[4], bfv[4];
#pragma unroll
        for (int mi = 0; mi < 4; mi++) af[mi] = *(const bf16x8*)(&As[cur][(wm * 4 + mi) * 512 + l * 8]);
#pragma unroll
        for (int nj = 0; nj < 4; nj++) bfv[nj] = *(const bf16x8*)(&Bs[cur][(wn * 4 + nj) * 512 + l * 8]);

        asm volatile("s_waitcnt lgkmcnt(0)" ::: "memory");
        __builtin_amdgcn_sched_barrier(0);     // rule 18: keep MFMA below the wait
        __builtin_amdgcn_s_barrier();          // all waves done reading buf[cur]
        asm volatile("" ::: "memory");         // pin the overwrite below the barrier

        if (kt + 2 < KT) {                     // overwrite buf[cur] with tile kt+2
            gload_lds16(aP,          &As[cur][w * 512]);
            gload_lds16(aP + step64, &As[cur][w * 512 + 2048]);
            gload_lds16(bP,          &Bs[cur][w * 512]);
            gload_lds16(bP + step64, &Bs[cur][w * 512 + 2048]);
            aP += 32; bP += 32;
        }
        __builtin_amdgcn_sched_barrier(0);     // issue loads before the MFMA cluster

#pragma unroll
        for (int mi = 0; mi < 4; mi++)
#pragma unroll
            for (int nj = 0; nj < 4; nj++) acc[mi][nj] = MFMA16(af[mi], bfv[nj], acc[mi][nj]);
    }

    float cb[4];
#pragma unroll
    for (int nj = 0; nj < 4; nj++) cb[nj] = bias[col0 + wn * 64 + nj * 16 + l15];

#pragma unroll
    for (int mi = 0; mi < 4; mi++) {
#pragma unroll
        for (int reg = 0; reg < 4; reg++) {
            long r = row0 + wm * 64 + mi * 16 + q4 * 4 + reg;
            bf16* cpn = C + r * (long)N + col0 + wn * 64 + l15;
#pragma unroll
            for (int nj = 0; nj < 4; nj++) {
                float v = acc[mi][nj][reg] + cb[nj];
                if (GELU) {
                    // tanh-gelu == v * sigmoid(2u), u = 0.79788456*(v + 0.044715 v^3)
                    float v2 = v * v;
                    float tt = v * fmaf(v2, -0.10294702f, -2.30218094f);
                    float e = __builtin_amdgcn_exp2f(tt);
                    v = v * __builtin_amdgcn_rcpf(1.f + e);
                }
                cpn[nj * 16] = (bf16)v;
            }
        }
    }
}

// ---------------------------------------------------------------- attention
// One wave per (window, head). qkv rows in window order.
__global__ __launch_bounds__(64) void attn_kernel(const bf16* __restrict__ qkv,
                                                  const float* __restrict__ bias16,
                                                  const float* __restrict__ logit_scale,
                                                  bf16* __restrict__ outp) {
    __shared__ bf16 P[64 * 72];
    __shared__ bf16 Vt[32 * 72];
    const int unit = blockIdx.x;
    const int w = unit >> 3, h = unit & 7;
    const int l = threadIdx.x;
    const int l15 = l & 15, q4 = l >> 4;
    const bf16* base = qkv + (long)w * 64 * 768;

    {  // stage V^T: lane l holds token l
        const bf16* vp = base + l * 768 + 512 + h * 32;
#pragma unroll
        for (int c = 0; c < 4; c++) {
            bf16x8 vv = *(const bf16x8*)(vp + c * 8);
#pragma unroll
            for (int j = 0; j < 8; j++) Vt[(c * 8 + j) * 72 + l] = vv[j];
        }
    }

    const float scale = __expf(fminf(logit_scale[h], 4.605170186f));

    bf16x8 qf[4], kf[4];
#pragma unroll
    for (int mi = 0; mi < 4; mi++) {  // l2-normalized Q fragments
        const bf16* p = base + (mi * 16 + l15) * 768 + h * 32 + q4 * 8;
        bf16x8 xv = *(const bf16x8*)p;
        float fv[8]; float ss = 0.f;
#pragma unroll
        for (int j = 0; j < 8; j++) { fv[j] = (float)xv[j]; ss += fv[j] * fv[j]; }
        ss += __shfl_xor(ss, 16); ss += __shfl_xor(ss, 32);
        float rs = rsqrtf(fmaxf(ss, 1e-12f));
#pragma unroll
        for (int j = 0; j < 8; j++) qf[mi][j] = (bf16)(fv[j] * rs);
    }
#pragma unroll
    for (int nj = 0; nj < 4; nj++) {  // l2-normalized K fragments
        const bf16* p = base + (nj * 16 + l15) * 768 + 256 + h * 32 + q4 * 8;
        bf16x8 xv = *(const bf16x8*)p;
        float fv[8]; float ss = 0.f;
#pragma unroll
        for (int j = 0; j < 8; j++) { fv[j] = (float)xv[j]; ss += fv[j] * fv[j]; }
        ss += __shfl_xor(ss, 16); ss += __shfl_xor(ss, 32);
        float rs = rsqrtf(fmaxf(ss, 1e-12f));
#pragma unroll
        for (int j = 0; j < 8; j++) kf[nj][j] = (bf16)(fv[j] * rs);
    }

    f32x4 acc[4][4];
#pragma unroll
    for (int i = 0; i < 4; i++)
#pragma unroll
        for (int j = 0; j < 4; j++)
#pragma unroll
            for (int r = 0; r < 4; r++) acc[i][j][r] = 0.f;
#pragma unroll
    for (int mi = 0; mi < 4; mi++)
#pragma unroll
        for (int nj = 0; nj < 4; nj++) acc[mi][nj] = MFMA16(qf[mi], kf[nj], acc[mi][nj]);

    // scale + CPB bias + shift mask
    const int widx = w & 63, wr = widx >> 3, wc = widx & 7;
    const bool edge = (wr == 7) || (wc == 7);
    int crid[4];
    if (edge) {
#pragma unroll
        for (int nj = 0; nj < 4; nj++) {
            int m = nj * 16 + l15;
            int R = wr * 8 + (m >> 3), Cc = wc * 8 + (m & 7);
            crid[nj] = ((R < 56) ? 0 : (R < 60 ? 1 : 2)) * 3 + ((Cc < 56) ? 0 : (Cc < 60 ? 1 : 2));
        }
    }
    const float* bh = bias16 + h * 4096;
#pragma unroll
    for (int mi = 0; mi < 4; mi++) {
#pragma unroll
        for (int reg = 0; reg < 4; reg++) {
            int n = mi * 16 + q4 * 4 + reg;
            const float* bp = bh + n * 64;
            int nrid = 0;
            if (edge) {
                int R = wr * 8 + (n >> 3), Cc = wc * 8 + (n & 7);
                nrid = ((R < 56) ? 0 : (R < 60 ? 1 : 2)) * 3 + ((Cc < 56) ? 0 : (Cc < 60 ? 1 : 2));
            }
#pragma unroll
            for (int nj = 0; nj < 4; nj++) {
                float v = acc[mi][nj][reg] * scale + bp[nj * 16 + l15];
                if (edge && nrid != crid[nj]) v -= 100.f;
                acc[mi][nj][reg] = v;
            }
        }
    }

    // row softmax (row = 16 lanes sharing q4, across 4 nj regs)
#pragma unroll
    for (int mi = 0; mi < 4; mi++) {
#pragma unroll
        for (int reg = 0; reg < 4; reg++) {
            float mx = fmaxf(fmaxf(acc[mi][0][reg], acc[mi][1][reg]),
                             fmaxf(acc[mi][2][reg], acc[mi][3][reg]));
            mx = fmaxf(mx, __shfl_xor(mx, 1));
            mx = fmaxf(mx, __shfl_xor(mx, 2));
            mx = fmaxf(mx, __shfl_xor(mx, 4));
            mx = fmaxf(mx, __shfl_xor(mx, 8));
            float s = 0.f;
#pragma unroll
            for (int nj = 0; nj < 4; nj++) {
                float e = __expf(acc[mi][nj][reg] - mx);
                acc[mi][nj][reg] = e; s += e;
            }
            s += __shfl_xor(s, 1); s += __shfl_xor(s, 2);
            s += __shfl_xor(s, 4); s += __shfl_xor(s, 8);
            float inv = 1.f / s;
            int n = mi * 16 + q4 * 4 + reg;
#pragma unroll
            for (int nj = 0; nj < 4; nj++)
                P[n * 72 + nj * 16 + l15] = (bf16)(acc[mi][nj][reg] * inv);
        }
    }
    __syncthreads();

    // O = P @ V  (K=64 in two 32-steps)
    f32x4 o[4][2];
#pragma unroll
    for (int i = 0; i < 4; i++)
#pragma unroll
        for (int j = 0; j < 2; j++)
#pragma unroll
            for (int r = 0; r < 4; r++) o[i][j][r] = 0.f;
#pragma unroll
    for (int ks = 0; ks < 2; ks++) {
        bf16x8 vf[2];
#pragma unroll
        for (int nj = 0; nj < 2; nj++) vf[nj] = *(const bf16x8*)(&Vt[(nj * 16 + l15) * 72 + ks * 32 + q4 * 8]);
#pragma unroll
        for (int mi = 0; mi < 4; mi++) {
            bf16x8 pf = *(const bf16x8*)(&P[(mi * 16 + l15) * 72 + ks * 32 + q4 * 8]);
#pragma unroll
            for (int nj = 0; nj < 2; nj++) o[mi][nj] = MFMA16(pf, vf[nj], o[mi][nj]);
        }
    }

    bf16* op = outp + (long)w * 64 * 256 + h * 32;
#pragma unroll
    for (int mi = 0; mi < 4; mi++)
#pragma unroll
        for (int reg = 0; reg < 4; reg++) {
            int tok = mi * 16 + q4 * 4 + reg;
#pragma unroll
            for (int nj = 0; nj < 2; nj++)
                op[tok * 256 + nj * 16 + l15] = (bf16)o[mi][nj][reg];
        }
}

// ---------------------------------------------------------------- norms
// norm1: rows in window order; scatter to orig order: x1 = x + LN(proj_out)
__global__ __launch_bounds__(256) void norm1_kernel(const bf16* __restrict__ pin,
                                                    const float* __restrict__ x,
                                                    const float* __restrict__ g,
                                                    const float* __restrict__ bb,
                                                    bf16* __restrict__ x1h) {
    const int tid = threadIdx.x;
    const int wid = tid >> 6, l = tid & 63;
    const long rl = (long)blockIdx.x * 4 + wid;
    bf16x4 v4 = *(const bf16x4*)(pin + rl * 256 + l * 4);
    float v[4]; float s = 0.f, sq = 0.f;
#pragma unroll
    for (int c = 0; c < 4; c++) { v[c] = (float)v4[c]; s += v[c]; sq += v[c] * v[c]; }
#pragma unroll
    for (int off = 1; off < 64; off <<= 1) { s += __shfl_xor(s, off); sq += __shfl_xor(sq, off); }
    float mu = s * 0.00390625f;
    float var = sq * 0.00390625f - mu * mu;
    float rstd = rsqrtf(var + 1e-6f);
    long orig = win2orig(rl);
    float4 xv = *(const float4*)(x + orig * 256 + l * 4);
    float4 gv = *(const float4*)(g + l * 4);
    float4 bv = *(const float4*)(bb + l * 4);
    bf16x4 oh;
    oh[0] = (bf16)(xv.x + ((v[0] - mu) * rstd * gv.x + bv.x));
    oh[1] = (bf16)(xv.y + ((v[1] - mu) * rstd * gv.y + bv.y));
    oh[2] = (bf16)(xv.z + ((v[2] - mu) * rstd * gv.z + bv.z));
    oh[3] = (bf16)(xv.w + ((v[3] - mu) * rstd * gv.w + bv.w));
    *(bf16x4*)(x1h + orig * 256 + l * 4) = oh;
}

// norm2: out = x1 + LN(fc2_out), all in orig order
__global__ __launch_bounds__(256) void norm2_kernel(const bf16* __restrict__ hin,
                                                    const bf16* __restrict__ x1h,
                                                    const float* __restrict__ g,
                                                    const float* __restrict__ bb,
                                                    float* __restrict__ outp) {
    const int tid = threadIdx.x;
    const int wid = tid >> 6, l = tid & 63;
    const long rl = (long)blockIdx.x * 4 + wid;
    bf16x4 v4 = *(const bf16x4*)(hin + rl * 256 + l * 4);
    float v[4]; float s = 0.f, sq = 0.f;
#pragma unroll
    for (int c = 0; c < 4; c++) { v[c] = (float)v4[c]; s += v[c]; sq += v[c] * v[c]; }
#pragma unroll
    for (int off = 1; off < 64; off <<= 1) { s += __shfl_xor(s, off); sq += __shfl_xor(sq, off); }
    float mu = s * 0.00390625f;
    float var = sq * 0.00390625f - mu * mu;
    float rstd = rsqrtf(var + 1e-6f);
    bf16x4 xv4 = *(const bf16x4*)(x1h + rl * 256 + l * 4);
    float4 gv = *(const float4*)(g + l * 4);
    float4 bv = *(const float4*)(bb + l * 4);
    float4 ov;
    ov.x = (float)xv4[0] + ((v[0] - mu) * rstd * gv.x + bv.x);
    ov.y = (float)xv4[1] + ((v[1] - mu) * rstd * gv.y + bv.y);
    ov.z = (float)xv4[2] + ((v[2] - mu) * rstd * gv.z + bv.z);
    ov.w = (float)xv4[3] + ((v[3] - mu) * rstd * gv.w + bv.w);
    *(float4*)(outp + rl * 256 + l * 4) = ov;
}

// ---------------------------------------------------------------- small prep
// gather rows (window order) from x (orig order, fp32), cast to bf16
__global__ __launch_bounds__(256) void gather_cast(const float* __restrict__ x,
                                                   bf16* __restrict__ out) {
    const int tid = threadIdx.x;
    const int wid = tid >> 6, l = tid & 63;
    const long rl = (long)blockIdx.x * 4 + wid;
    long orig = win2orig(rl);
    float4 v = *(const float4*)(x + orig * 256 + l * 4);
    bf16x4 o = {(bf16)v.x, (bf16)v.y, (bf16)v.z, (bf16)v.w};
    *(bf16x4*)(out + rl * 256 + l * 4) = o;
}

// out[N,K] = cast(in[K,N]^T)
__global__ void transpose_cast(const float* __restrict__ in, bf16* __restrict__ out, int K, int N) {
    int id = blockIdx.x * 256 + threadIdx.x;
    if (id < K * N) {
        int n = id / K, k = id - n * K;
        out[id] = (bf16)in[k * N + n];
    }
}

__global__ void build_qkv_bias(const float* __restrict__ qb, const float* __restrict__ vb,
                               float* __restrict__ out) {
    int i = blockIdx.x * 256 + threadIdx.x;
    if (i < 768) out[i] = (i < 256) ? qb[i] : ((i < 512) ? 0.f : vb[i - 512]);
}

__device__ __forceinline__ float cpcoord(int d) {
    float v = (float)d * (8.0f / 7.0f);
    float r = log2f(fabsf(v) + 1.0f) * (1.0f / 3.0f);
    return v < 0.f ? -r : r;
}

__global__ void cpb1(const float* __restrict__ w1, const float* __restrict__ b1,
                     const float* __restrict__ w2, float* __restrict__ tbl) {
    int a = threadIdx.x;
    if (a >= 225) return;
    int i = a / 15, j = a - i * 15;
    float t0 = cpcoord(i - 7), t1 = cpcoord(j - 7);
    float acc[8];
#pragma unroll
    for (int o = 0; o < 8; o++) acc[o] = 0.f;
    for (int jj = 0; jj < 512; jj++) {
        float hv = fmaf(t0, w1[jj], fmaf(t1, w1[512 + jj], b1[jj]));
        hv = fmaxf(hv, 0.f);
#pragma unroll
        for (int o = 0; o < 8; o++) acc[o] = fmaf(hv, w2[jj * 8 + o], acc[o]);
    }
#pragma unroll
    for (int o = 0; o < 8; o++) tbl[a * 8 + o] = acc[o];
}

__global__ void cpb2(const float* __restrict__ tbl, float* __restrict__ bias16) {
    int id = blockIdx.x * 256 + threadIdx.x;
    if (id >= 32768) return;
    int h = id >> 12, n = (id >> 6) & 63, m = id & 63;
    int r0 = (n >> 3) - (m >> 3) + 7;
    int r1 = (n & 7) - (m & 7) + 7;
    float v = tbl[(r0 * 15 + r1) * 8 + h];
    bias16[id] = 16.f / (1.f + __expf(-v));
}

// ---------------------------------------------------------------- launch
extern "C" void kernel_launch(void* const* d_in, const int* in_sizes, int n_in,
                              void* d_out, int out_size, void* d_ws, size_t ws_size,
                              hipStream_t stream) {
    const float* x   = (const float*)d_in[0];
    const float* qkvw= (const float*)d_in[1];
    const float* qb  = (const float*)d_in[2];
    const float* vb  = (const float*)d_in[3];
    const float* ls  = (const float*)d_in[4];
    const float* cw1 = (const float*)d_in[5];
    const float* cb1 = (const float*)d_in[6];
    const float* cw2 = (const float*)d_in[7];
    const float* pw  = (const float*)d_in[8];
    const float* pb  = (const float*)d_in[9];
    const float* n1s = (const float*)d_in[10];
    const float* n1b = (const float*)d_in[11];
    const float* n2s = (const float*)d_in[12];
    const float* n2b = (const float*)d_in[13];
    const float* f1w = (const float*)d_in[14];
    const float* f1b = (const float*)d_in[15];
    const float* f2w = (const float*)d_in[16];
    const float* f2b = (const float*)d_in[17];

    char* ws = (char*)d_ws;
    if (ws_size < 471859200UL) return;  // peak scratch = 450 MiB (harness gives 512 MiB)
    bf16*  qkvBt   = (bf16*)(ws + 0);
    bf16*  projBt  = (bf16*)(ws + 393216);
    bf16*  fc1Bt   = (bf16*)(ws + 524288);
    bf16*  fc2Bt   = (bf16*)(ws + 1048576);
    float* qkvBias = (float*)(ws + 1572864);
    float* cpbTbl  = (float*)(ws + 1575936);
    float* bias16  = (float*)(ws + 1583360);
    // big buffers (offsets in bytes from ws)
    bf16* xbf     = (bf16*)(ws + 2097152);     // 131072x256  (window order), 64 MiB
    bf16* qkvBuf  = (bf16*)(ws + 69206016);    // 131072x768, 192 MiB
    bf16* attnOut = (bf16*)(ws + 270532608);   // 131072x256, 64 MiB
    bf16* projOut = (bf16*)(ws + 337641472);   // 131072x256, 64 MiB
    bf16* x1h     = (bf16*)(ws + 404750336);   // 131072x256 (orig order), 64 MiB
    bf16* hBuf    = (bf16*)(ws + 2097152);     // 131072x1024, 256 MiB (aliases xbf+qkvBuf, dead)
    bf16* fc2Out  = (bf16*)(ws + 337641472);   // aliases projOut (dead after norm1)

    transpose_cast<<<768, 256, 0, stream>>>(qkvw, qkvBt, 256, 768);
    transpose_cast<<<256, 256, 0, stream>>>(pw, projBt, 256, 256);
    transpose_cast<<<1024, 256, 0, stream>>>(f1w, fc1Bt, 256, 1024);
    transpose_cast<<<1024, 256, 0, stream>>>(f2w, fc2Bt, 1024, 256);
    build_qkv_bias<<<3, 256, 0, stream>>>(qb, vb, qkvBias);
    cpb1<<<1, 256, 0, stream>>>(cw1, cb1, cw2, cpbTbl);
    cpb2<<<128, 256, 0, stream>>>(cpbTbl, bias16);

    gather_cast<<<32768, 256, 0, stream>>>(x, xbf);
    gemm_bt<0><<<dim3(6, 1024), 256, 0, stream>>>(xbf, qkvBt, qkvBias, qkvBuf, 131072, 768, 256);
    attn_kernel<<<16384, 64, 0, stream>>>(qkvBuf, bias16, ls, attnOut);
    gemm_bt<0><<<dim3(2, 1024), 256, 0, stream>>>(attnOut, projBt, pb, projOut, 131072, 256, 256);
    norm1_kernel<<<32768, 256, 0, stream>>>(projOut, x, n1s, n1b, x1h);
    gemm_bt<1><<<dim3(8, 1024), 256, 0, stream>>>(x1h, fc1Bt, f1b, hBuf, 131072, 1024, 256);
    gemm_bt<0><<<dim3(2, 1024), 256, 0, stream>>>(hBuf, fc2Bt, f2b, fc2Out, 131072, 256, 1024);
    norm2_kernel<<<32768, 256, 0, stream>>>(fc2Out, x1h, n2s, n2b, (float*)d_out);
}

// Round 3
// 933.380 us; speedup vs baseline: 1.1329x; 1.1034x over previous
//
#include <hip/hip_runtime.h>

typedef __bf16 bf16;
typedef __bf16 bf16x8 __attribute__((ext_vector_type(8)));
typedef __bf16 bf16x4 __attribute__((ext_vector_type(4)));
typedef float  f32x4  __attribute__((ext_vector_type(4)));

#define MFMA16(a, b, c) __builtin_amdgcn_mfma_f32_16x16x32_bf16(a, b, c, 0, 0, 0)

__device__ __forceinline__ void gload_lds16(const void* g, void* l) {
    __builtin_amdgcn_global_load_lds((const __attribute__((address_space(1))) void*)g,
                                     (__attribute__((address_space(3))) void*)l, 16, 0, 0);
}

// window-order row -> original-order row (inverse of roll(-4,-4)+partition)
__device__ __forceinline__ long win2orig(long r) {
    long b = r >> 12; int rem = (int)(r & 4095);
    int widx = rem >> 6, t = rem & 63;
    int rp = ((widx >> 3) << 3) + (t >> 3), cp = ((widx & 7) << 3) + (t & 7);
    int rr = (rp + 4) & 63, cc = (cp + 4) & 63;
    return (b << 12) + rr * 64 + cc;
}

// ---------------------------------------------------------------- GEMM
// C[M,N] = A[M,K] (bf16) * Bt[N,K]^T (bf16) + bias, optional gelu.
// Round 3: 256x256 tile, BK=64, 8 waves (512 thr), 128 KiB LDS (2x dbuf).
// Same verified sync skeleton as R2 (counted vmcnt + raw barriers), scaled:
// 64 MFMA per barrier-pair instead of 16 (m230: 256^2+2ph = 682 TF class).
// LDS layout stays fragment-linear (conflict-free): A-tile = 16 groups of
// (16 rows x 64 k), group g sub-block kk at As[g*1024 + kk*512 + lane*8].
// Wave w stages units (g = w*2 + i>>1, kk = i&1), i=0..3 -> dst w*2048+i*512.
template <int GELU>
__global__ __launch_bounds__(512, 2) void gemm_bt(const bf16* __restrict__ A,
                                                  const bf16* __restrict__ Bt,
                                                  const float* __restrict__ bias,
                                                  bf16* __restrict__ C,
                                                  int M, int N, int K) {
    __shared__ bf16 As[2][16384];
    __shared__ bf16 Bs[2][16384];
    const int t = threadIdx.x;
    const int w = t >> 6, l = t & 63;
    const int l15 = l & 15, q4 = l >> 4;
    const int wm = w >> 2, wn = w & 3;

    // T1: chunked XCD swizzle (all launches have nwg % 8 == 0).
    const unsigned gx = gridDim.x;
    const unsigned nwg = gx * gridDim.y;
    const unsigned id0 = blockIdx.y * gx + blockIdx.x;
    const unsigned swz = (id0 & 7u) * (nwg >> 3) + (id0 >> 3);
    const unsigned bx = swz % gx, by = swz / gx;

    const long row0 = (long)by * 256;
    const int col0 = (int)bx * 256;

    // staging sources: wave w covers A-units and B-units (w*4 .. w*4+3)
    const bf16* aSrc0; const bf16* aSrc1; const bf16* aSrc2; const bf16* aSrc3;
    const bf16* bSrc0; const bf16* bSrc1; const bf16* bSrc2; const bf16* bSrc3;
    {
        const long ar = row0 + (w * 2) * 16 + l15;
        const long br = (long)col0 + (w * 2) * 16 + l15;
        aSrc0 = A + ar * (long)K + q4 * 8;
        aSrc1 = A + ar * (long)K + 32 + q4 * 8;
        aSrc2 = A + (ar + 16) * (long)K + q4 * 8;
        aSrc3 = A + (ar + 16) * (long)K + 32 + q4 * 8;
        bSrc0 = Bt + br * (long)K + q4 * 8;
        bSrc1 = Bt + br * (long)K + 32 + q4 * 8;
        bSrc2 = Bt + (br + 16) * (long)K + q4 * 8;
        bSrc3 = Bt + (br + 16) * (long)K + 32 + q4 * 8;
    }

#define STAGE(buf)                                         \
    do {                                                   \
        gload_lds16(aSrc0, &As[buf][w * 2048 + 0 * 512]);  \
        gload_lds16(aSrc1, &As[buf][w * 2048 + 1 * 512]);  \
        gload_lds16(aSrc2, &As[buf][w * 2048 + 2 * 512]);  \
        gload_lds16(aSrc3, &As[buf][w * 2048 + 3 * 512]);  \
        gload_lds16(bSrc0, &Bs[buf][w * 2048 + 0 * 512]);  \
        gload_lds16(bSrc1, &Bs[buf][w * 2048 + 1 * 512]);  \
        gload_lds16(bSrc2, &Bs[buf][w * 2048 + 2 * 512]);  \
        gload_lds16(bSrc3, &Bs[buf][w * 2048 + 3 * 512]);  \
        aSrc0 += 64; aSrc1 += 64; aSrc2 += 64; aSrc3 += 64;\
        bSrc0 += 64; bSrc1 += 64; bSrc2 += 64; bSrc3 += 64;\
    } while (0)

    f32x4 acc[8][4];
#pragma unroll
    for (int i = 0; i < 8; i++)
#pragma unroll
        for (int j = 0; j < 4; j++)
#pragma unroll
            for (int r = 0; r < 4; r++) acc[i][j][r] = 0.f;

    const int KT = K >> 6;  // call sites: KT = 4 or 16

    // prologue: 2-deep prefetch (tiles 0 and 1), no drain.
    STAGE(0);
    STAGE(1);

    for (int kt = 0; kt < KT; ++kt) {
        const int cur = kt & 1;
        // wait for tile kt's 8 loads only; tile kt+1's 8 stay in flight.
        if (kt < KT - 1) { asm volatile("s_waitcnt vmcnt(8)" ::: "memory"); }
        else             { asm volatile("s_waitcnt vmcnt(0)" ::: "memory"); }
        __builtin_amdgcn_s_barrier();          // all waves' tile-kt loads landed
        asm volatile("" ::: "memory");         // pin ds_read below the barrier

        bf16x8 af[8], bfv[4];
        // ---- kk = 0 sub-step
#pragma unroll
        for (int mi = 0; mi < 8; mi++) af[mi] = *(const bf16x8*)(&As[cur][(wm * 8 + mi) * 1024 + l * 8]);
#pragma unroll
        for (int nj = 0; nj < 4; nj++) bfv[nj] = *(const bf16x8*)(&Bs[cur][(wn * 4 + nj) * 1024 + l * 8]);
        asm volatile("s_waitcnt lgkmcnt(0)" ::: "memory");
        __builtin_amdgcn_sched_barrier(0);     // rule 18: keep MFMA below the wait
#pragma unroll
        for (int mi = 0; mi < 8; mi++)
#pragma unroll
            for (int nj = 0; nj < 4; nj++) acc[mi][nj] = MFMA16(af[mi], bfv[nj], acc[mi][nj]);

        // ---- kk = 1 sub-step (k-offset +32 -> LDS +512)
#pragma unroll
        for (int mi = 0; mi < 8; mi++) af[mi] = *(const bf16x8*)(&As[cur][(wm * 8 + mi) * 1024 + 512 + l * 8]);
#pragma unroll
        for (int nj = 0; nj < 4; nj++) bfv[nj] = *(const bf16x8*)(&Bs[cur][(wn * 4 + nj) * 1024 + 512 + l * 8]);
        asm volatile("s_waitcnt lgkmcnt(0)" ::: "memory");
        __builtin_amdgcn_sched_barrier(0);
        __builtin_amdgcn_s_barrier();          // all waves done reading buf[cur]
        asm volatile("" ::: "memory");         // pin the overwrite below the barrier

        if (kt + 2 < KT) STAGE(cur);           // overwrite buf[cur] with tile kt+2
        __builtin_amdgcn_sched_barrier(0);     // issue loads before the MFMA cluster

#pragma unroll
        for (int mi = 0; mi < 8; mi++)
#pragma unroll
            for (int nj = 0; nj < 4; nj++) acc[mi][nj] = MFMA16(af[mi], bfv[nj], acc[mi][nj]);
    }
#undef STAGE

    float cb[4];
#pragma unroll
    for (int nj = 0; nj < 4; nj++) cb[nj] = bias[col0 + wn * 64 + nj * 16 + l15];

#pragma unroll
    for (int mi = 0; mi < 8; mi++) {
#pragma unroll
        for (int reg = 0; reg < 4; reg++) {
            long r = row0 + wm * 128 + mi * 16 + q4 * 4 + reg;
            bf16* cpn = C + r * (long)N + col0 + wn * 64 + l15;
#pragma unroll
            for (int nj = 0; nj < 4; nj++) {
                float v = acc[mi][nj][reg] + cb[nj];
                if (GELU) {
                    // tanh-gelu == v * sigmoid(2u), u = 0.79788456*(v + 0.044715 v^3)
                    float v2 = v * v;
                    float tt = v * fmaf(v2, -0.10294702f, -2.30218094f);
                    float e = __builtin_amdgcn_exp2f(tt);
                    v = v * __builtin_amdgcn_rcpf(1.f + e);
                }
                cpn[nj * 16] = (bf16)v;
            }
        }
    }
}

// ---------------------------------------------------------------- attention
// One wave per (window, head). qkv rows in window order.
__global__ __launch_bounds__(64) void attn_kernel(const bf16* __restrict__ qkv,
                                                  const float* __restrict__ bias16,
                                                  const float* __restrict__ logit_scale,
                                                  bf16* __restrict__ outp) {
    __shared__ bf16 P[64 * 72];
    __shared__ bf16 Vt[32 * 72];
    const int unit = blockIdx.x;
    const int w = unit >> 3, h = unit & 7;
    const int l = threadIdx.x;
    const int l15 = l & 15, q4 = l >> 4;
    const bf16* base = qkv + (long)w * 64 * 768;

    {  // stage V^T: lane l holds token l
        const bf16* vp = base + l * 768 + 512 + h * 32;
#pragma unroll
        for (int c = 0; c < 4; c++) {
            bf16x8 vv = *(const bf16x8*)(vp + c * 8);
#pragma unroll
            for (int j = 0; j < 8; j++) Vt[(c * 8 + j) * 72 + l] = vv[j];
        }
    }

    const float scale = __expf(fminf(logit_scale[h], 4.605170186f));

    bf16x8 qf[4], kf[4];
#pragma unroll
    for (int mi = 0; mi < 4; mi++) {  // l2-normalized Q fragments
        const bf16* p = base + (mi * 16 + l15) * 768 + h * 32 + q4 * 8;
        bf16x8 xv = *(const bf16x8*)p;
        float fv[8]; float ss = 0.f;
#pragma unroll
        for (int j = 0; j < 8; j++) { fv[j] = (float)xv[j]; ss += fv[j] * fv[j]; }
        ss += __shfl_xor(ss, 16); ss += __shfl_xor(ss, 32);
        float rs = rsqrtf(fmaxf(ss, 1e-12f));
#pragma unroll
        for (int j = 0; j < 8; j++) qf[mi][j] = (bf16)(fv[j] * rs);
    }
#pragma unroll
    for (int nj = 0; nj < 4; nj++) {  // l2-normalized K fragments
        const bf16* p = base + (nj * 16 + l15) * 768 + 256 + h * 32 + q4 * 8;
        bf16x8 xv = *(const bf16x8*)p;
        float fv[8]; float ss = 0.f;
#pragma unroll
        for (int j = 0; j < 8; j++) { fv[j] = (float)xv[j]; ss += fv[j] * fv[j]; }
        ss += __shfl_xor(ss, 16); ss += __shfl_xor(ss, 32);
        float rs = rsqrtf(fmaxf(ss, 1e-12f));
#pragma unroll
        for (int j = 0; j < 8; j++) kf[nj][j] = (bf16)(fv[j] * rs);
    }

    f32x4 acc[4][4];
#pragma unroll
    for (int i = 0; i < 4; i++)
#pragma unroll
        for (int j = 0; j < 4; j++)
#pragma unroll
            for (int r = 0; r < 4; r++) acc[i][j][r] = 0.f;
#pragma unroll
    for (int mi = 0; mi < 4; mi++)
#pragma unroll
        for (int nj = 0; nj < 4; nj++) acc[mi][nj] = MFMA16(qf[mi], kf[nj], acc[mi][nj]);

    // scale + CPB bias + shift mask
    const int widx = w & 63, wr = widx >> 3, wc = widx & 7;
    const bool edge = (wr == 7) || (wc == 7);
    int crid[4];
    if (edge) {
#pragma unroll
        for (int nj = 0; nj < 4; nj++) {
            int m = nj * 16 + l15;
            int R = wr * 8 + (m >> 3), Cc = wc * 8 + (m & 7);
            crid[nj] = ((R < 56) ? 0 : (R < 60 ? 1 : 2)) * 3 + ((Cc < 56) ? 0 : (Cc < 60 ? 1 : 2));
        }
    }
    const float* bh = bias16 + h * 4096;
#pragma unroll
    for (int mi = 0; mi < 4; mi++) {
#pragma unroll
        for (int reg = 0; reg < 4; reg++) {
            int n = mi * 16 + q4 * 4 + reg;
            const float* bp = bh + n * 64;
            int nrid = 0;
            if (edge) {
                int R = wr * 8 + (n >> 3), Cc = wc * 8 + (n & 7);
                nrid = ((R < 56) ? 0 : (R < 60 ? 1 : 2)) * 3 + ((Cc < 56) ? 0 : (Cc < 60 ? 1 : 2));
            }
#pragma unroll
            for (int nj = 0; nj < 4; nj++) {
                float v = acc[mi][nj][reg] * scale + bp[nj * 16 + l15];
                if (edge && nrid != crid[nj]) v -= 100.f;
                acc[mi][nj][reg] = v;
            }
        }
    }

    // row softmax (row = 16 lanes sharing q4, across 4 nj regs)
#pragma unroll
    for (int mi = 0; mi < 4; mi++) {
#pragma unroll
        for (int reg = 0; reg < 4; reg++) {
            float mx = fmaxf(fmaxf(acc[mi][0][reg], acc[mi][1][reg]),
                             fmaxf(acc[mi][2][reg], acc[mi][3][reg]));
            mx = fmaxf(mx, __shfl_xor(mx, 1));
            mx = fmaxf(mx, __shfl_xor(mx, 2));
            mx = fmaxf(mx, __shfl_xor(mx, 4));
            mx = fmaxf(mx, __shfl_xor(mx, 8));
            float s = 0.f;
#pragma unroll
            for (int nj = 0; nj < 4; nj++) {
                float e = __expf(acc[mi][nj][reg] - mx);
                acc[mi][nj][reg] = e; s += e;
            }
            s += __shfl_xor(s, 1); s += __shfl_xor(s, 2);
            s += __shfl_xor(s, 4); s += __shfl_xor(s, 8);
            float inv = 1.f / s;
            int n = mi * 16 + q4 * 4 + reg;
#pragma unroll
            for (int nj = 0; nj < 4; nj++)
                P[n * 72 + nj * 16 + l15] = (bf16)(acc[mi][nj][reg] * inv);
        }
    }
    __syncthreads();

    // O = P @ V  (K=64 in two 32-steps)
    f32x4 o[4][2];
#pragma unroll
    for (int i = 0; i < 4; i++)
#pragma unroll
        for (int j = 0; j < 2; j++)
#pragma unroll
            for (int r = 0; r < 4; r++) o[i][j][r] = 0.f;
#pragma unroll
    for (int ks = 0; ks < 2; ks++) {
        bf16x8 vf[2];
#pragma unroll
        for (int nj = 0; nj < 2; nj++) vf[nj] = *(const bf16x8*)(&Vt[(nj * 16 + l15) * 72 + ks * 32 + q4 * 8]);
#pragma unroll
        for (int mi = 0; mi < 4; mi++) {
            bf16x8 pf = *(const bf16x8*)(&P[(mi * 16 + l15) * 72 + ks * 32 + q4 * 8]);
#pragma unroll
            for (int nj = 0; nj < 2; nj++) o[mi][nj] = MFMA16(pf, vf[nj], o[mi][nj]);
        }
    }

    bf16* op = outp + (long)w * 64 * 256 + h * 32;
#pragma unroll
    for (int mi = 0; mi < 4; mi++)
#pragma unroll
        for (int reg = 0; reg < 4; reg++) {
            int tok = mi * 16 + q4 * 4 + reg;
#pragma unroll
            for (int nj = 0; nj < 2; nj++)
                op[tok * 256 + nj * 16 + l15] = (bf16)o[mi][nj][reg];
        }
}

// ---------------------------------------------------------------- norms
// norm1: rows in window order; scatter to orig order: x1 = x + LN(proj_out)
__global__ __launch_bounds__(256) void norm1_kernel(const bf16* __restrict__ pin,
                                                    const float* __restrict__ x,
                                                    const float* __restrict__ g,
                                                    const float* __restrict__ bb,
                                                    bf16* __restrict__ x1h) {
    const int tid = threadIdx.x;
    const int wid = tid >> 6, l = tid & 63;
    const long rl = (long)blockIdx.x * 4 + wid;
    bf16x4 v4 = *(const bf16x4*)(pin + rl * 256 + l * 4);
    float v[4]; float s = 0.f, sq = 0.f;
#pragma unroll
    for (int c = 0; c < 4; c++) { v[c] = (float)v4[c]; s += v[c]; sq += v[c] * v[c]; }
#pragma unroll
    for (int off = 1; off < 64; off <<= 1) { s += __shfl_xor(s, off); sq += __shfl_xor(sq, off); }
    float mu = s * 0.00390625f;
    float var = sq * 0.00390625f - mu * mu;
    float rstd = rsqrtf(var + 1e-6f);
    long orig = win2orig(rl);
    float4 xv = *(const float4*)(x + orig * 256 + l * 4);
    float4 gv = *(const float4*)(g + l * 4);
    float4 bv = *(const float4*)(bb + l * 4);
    bf16x4 oh;
    oh[0] = (bf16)(xv.x + ((v[0] - mu) * rstd * gv.x + bv.x));
    oh[1] = (bf16)(xv.y + ((v[1] - mu) * rstd * gv.y + bv.y));
    oh[2] = (bf16)(xv.z + ((v[2] - mu) * rstd * gv.z + bv.z));
    oh[3] = (bf16)(xv.w + ((v[3] - mu) * rstd * gv.w + bv.w));
    *(bf16x4*)(x1h + orig * 256 + l * 4) = oh;
}

// norm2: out = x1 + LN(fc2_out), all in orig order
__global__ __launch_bounds__(256) void norm2_kernel(const bf16* __restrict__ hin,
                                                    const bf16* __restrict__ x1h,
                                                    const float* __restrict__ g,
                                                    const float* __restrict__ bb,
                                                    float* __restrict__ outp) {
    const int tid = threadIdx.x;
    const int wid = tid >> 6, l = tid & 63;
    const long rl = (long)blockIdx.x * 4 + wid;
    bf16x4 v4 = *(const bf16x4*)(hin + rl * 256 + l * 4);
    float v[4]; float s = 0.f, sq = 0.f;
#pragma unroll
    for (int c = 0; c < 4; c++) { v[c] = (float)v4[c]; s += v[c]; sq += v[c] * v[c]; }
#pragma unroll
    for (int off = 1; off < 64; off <<= 1) { s += __shfl_xor(s, off); sq += __shfl_xor(sq, off); }
    float mu = s * 0.00390625f;
    float var = sq * 0.00390625f - mu * mu;
    float rstd = rsqrtf(var + 1e-6f);
    bf16x4 xv4 = *(const bf16x4*)(x1h + rl * 256 + l * 4);
    float4 gv = *(const float4*)(g + l * 4);
    float4 bv = *(const float4*)(bb + l * 4);
    float4 ov;
    ov.x = (float)xv4[0] + ((v[0] - mu) * rstd * gv.x + bv.x);
    ov.y = (float)xv4[1] + ((v[1] - mu) * rstd * gv.y + bv.y);
    ov.z = (float)xv4[2] + ((v[2] - mu) * rstd * gv.z + bv.z);
    ov.w = (float)xv4[3] + ((v[3] - mu) * rstd * gv.w + bv.w);
    *(float4*)(outp + rl * 256 + l * 4) = ov;
}

// ---------------------------------------------------------------- small prep
// gather rows (window order) from x (orig order, fp32), cast to bf16
__global__ __launch_bounds__(256) void gather_cast(const float* __restrict__ x,
                                                   bf16* __restrict__ out) {
    const int tid = threadIdx.x;
    const int wid = tid >> 6, l = tid & 63;
    const long rl = (long)blockIdx.x * 4 + wid;
    long orig = win2orig(rl);
    float4 v = *(const float4*)(x + orig * 256 + l * 4);
    bf16x4 o = {(bf16)v.x, (bf16)v.y, (bf16)v.z, (bf16)v.w};
    *(bf16x4*)(out + rl * 256 + l * 4) = o;
}

// out[N,K] = cast(in[K,N]^T)
__global__ void transpose_cast(const float* __restrict__ in, bf16* __restrict__ out, int K, int N) {
    int id = blockIdx.x * 256 + threadIdx.x;
    if (id < K * N) {
        int n = id / K, k = id - n * K;
        out[id] = (bf16)in[k * N + n];
    }
}

__global__ void build_qkv_bias(const float* __restrict__ qb, const float* __restrict__ vb,
                               float* __restrict__ out) {
    int i = blockIdx.x * 256 + threadIdx.x;
    if (i < 768) out[i] = (i < 256) ? qb[i] : ((i < 512) ? 0.f : vb[i - 512]);
}

__device__ __forceinline__ float cpcoord(int d) {
    float v = (float)d * (8.0f / 7.0f);
    float r = log2f(fabsf(v) + 1.0f) * (1.0f / 3.0f);
    return v < 0.f ? -r : r;
}

__global__ void cpb1(const float* __restrict__ w1, const float* __restrict__ b1,
                     const float* __restrict__ w2, float* __restrict__ tbl) {
    int a = threadIdx.x;
    if (a >= 225) return;
    int i = a / 15, j = a - i * 15;
    float t0 = cpcoord(i - 7), t1 = cpcoord(j - 7);
    float acc[8];
#pragma unroll
    for (int o = 0; o < 8; o++) acc[o] = 0.f;
    for (int jj = 0; jj < 512; jj++) {
        float hv = fmaf(t0, w1[jj], fmaf(t1, w1[512 + jj], b1[jj]));
        hv = fmaxf(hv, 0.f);
#pragma unroll
        for (int o = 0; o < 8; o++) acc[o] = fmaf(hv, w2[jj * 8 + o], acc[o]);
    }
#pragma unroll
    for (int o = 0; o < 8; o++) tbl[a * 8 + o] = acc[o];
}

__global__ void cpb2(const float* __restrict__ tbl, float* __restrict__ bias16) {
    int id = blockIdx.x * 256 + threadIdx.x;
    if (id >= 32768) return;
    int h = id >> 12, n = (id >> 6) & 63, m = id & 63;
    int r0 = (n >> 3) - (m >> 3) + 7;
    int r1 = (n & 7) - (m & 7) + 7;
    float v = tbl[(r0 * 15 + r1) * 8 + h];
    bias16[id] = 16.f / (1.f + __expf(-v));
}

// ---------------------------------------------------------------- launch
extern "C" void kernel_launch(void* const* d_in, const int* in_sizes, int n_in,
                              void* d_out, int out_size, void* d_ws, size_t ws_size,
                              hipStream_t stream) {
    const float* x   = (const float*)d_in[0];
    const float* qkvw= (const float*)d_in[1];
    const float* qb  = (const float*)d_in[2];
    const float* vb  = (const float*)d_in[3];
    const float* ls  = (const float*)d_in[4];
    const float* cw1 = (const float*)d_in[5];
    const float* cb1 = (const float*)d_in[6];
    const float* cw2 = (const float*)d_in[7];
    const float* pw  = (const float*)d_in[8];
    const float* pb  = (const float*)d_in[9];
    const float* n1s = (const float*)d_in[10];
    const float* n1b = (const float*)d_in[11];
    const float* n2s = (const float*)d_in[12];
    const float* n2b = (const float*)d_in[13];
    const float* f1w = (const float*)d_in[14];
    const float* f1b = (const float*)d_in[15];
    const float* f2w = (const float*)d_in[16];
    const float* f2b = (const float*)d_in[17];

    char* ws = (char*)d_ws;
    if (ws_size < 471859200UL) return;  // peak scratch = 450 MiB (harness gives 512 MiB)
    bf16*  qkvBt   = (bf16*)(ws + 0);
    bf16*  projBt  = (bf16*)(ws + 393216);
    bf16*  fc1Bt   = (bf16*)(ws + 524288);
    bf16*  fc2Bt   = (bf16*)(ws + 1048576);
    float* qkvBias = (float*)(ws + 1572864);
    float* cpbTbl  = (float*)(ws + 1575936);
    float* bias16  = (float*)(ws + 1583360);
    // big buffers (offsets in bytes from ws)
    bf16* xbf     = (bf16*)(ws + 2097152);     // 131072x256  (window order), 64 MiB
    bf16* qkvBuf  = (bf16*)(ws + 69206016);    // 131072x768, 192 MiB
    bf16* attnOut = (bf16*)(ws + 270532608);   // 131072x256, 64 MiB
    bf16* projOut = (bf16*)(ws + 337641472);   // 131072x256, 64 MiB
    bf16* x1h     = (bf16*)(ws + 404750336);   // 131072x256 (orig order), 64 MiB
    bf16* hBuf    = (bf16*)(ws + 2097152);     // 131072x1024, 256 MiB (aliases xbf+qkvBuf, dead)
    bf16* fc2Out  = (bf16*)(ws + 337641472);   // aliases projOut (dead after norm1)

    transpose_cast<<<768, 256, 0, stream>>>(qkvw, qkvBt, 256, 768);
    transpose_cast<<<256, 256, 0, stream>>>(pw, projBt, 256, 256);
    transpose_cast<<<1024, 256, 0, stream>>>(f1w, fc1Bt, 256, 1024);
    transpose_cast<<<1024, 256, 0, stream>>>(f2w, fc2Bt, 1024, 256);
    build_qkv_bias<<<3, 256, 0, stream>>>(qb, vb, qkvBias);
    cpb1<<<1, 256, 0, stream>>>(cw1, cb1, cw2, cpbTbl);
    cpb2<<<128, 256, 0, stream>>>(cpbTbl, bias16);

    gather_cast<<<32768, 256, 0, stream>>>(x, xbf);
    gemm_bt<0><<<dim3(3, 512), 512, 0, stream>>>(xbf, qkvBt, qkvBias, qkvBuf, 131072, 768, 256);
    attn_kernel<<<16384, 64, 0, stream>>>(qkvBuf, bias16, ls, attnOut);
    gemm_bt<0><<<dim3(1, 512), 512, 0, stream>>>(attnOut, projBt, pb, projOut, 131072, 256, 256);
    norm1_kernel<<<32768, 256, 0, stream>>>(projOut, x, n1s, n1b, x1h);
    gemm_bt<1><<<dim3(4, 512), 512, 0, stream>>>(x1h, fc1Bt, f1b, hBuf, 131072, 1024, 256);
    gemm_bt<0><<<dim3(1, 512), 512, 0, stream>>>(hBuf, fc2Bt, f2b, fc2Out, 131072, 256, 1024);
    norm2_kernel<<<32768, 256, 0, stream>>>(fc2Out, x1h, n2s, n2b, (float*)d_out);
}